// Round 1
// baseline (302.422 us; speedup 1.0000x reference)
//
#include <hip/hip_runtime.h>

// Problem constants (from reference):
//   B=4, SEQ=4096, D=64, BS=32, V=512, R=128, P = B*R*(R+1)/2 = 33024
#define Bn   4
#define SEQn 4096
#define Dn   64
#define BSn  32
#define Vn   512

// ---------------- Phase 1: scores[b][m][v] = sum_d q[b][m][d] * emb[b][v][d]
// Block tile: 64 m x 128 v, 256 threads, per-thread 8m x 4v register tile.
// grid = (SEQ/64) * B * (V/128) = 64*4*4 = 1024 blocks.
#define TM  64
#define TV  128
#define THM 8
#define THV 4

__global__ __launch_bounds__(256) void scores_kernel(
    const float* __restrict__ q, const float* __restrict__ emb,
    float* __restrict__ scores)
{
  __shared__ float sq[TM * Dn];            // [m][d], 16 KB
  __shared__ float semb[Dn * (TV + 1)];    // [d][v] +1 pad, ~33 KB

  int blk  = blockIdx.x;
  int vblk = blk & 3;           // V/TV  = 4
  int bblk = (blk >> 2) & 3;    // B     = 4
  int mblk = blk >> 4;          // SEQ/TM = 64
  int m0 = mblk * TM;
  int v0 = vblk * TV;

  const float* qbase = q   + ((size_t)bblk * SEQn + m0) * Dn;
  const float* ebase = emb + ((size_t)bblk * Vn   + v0) * Dn;

  // stage q tile (natural [m][d] layout): 4096 floats -> 1024 float4
  {
    const float4* g = (const float4*)qbase;
    float4*       s = (float4*)sq;
    for (int t = threadIdx.x; t < TM * Dn / 4; t += 256) s[t] = g[t];
  }
  // stage emb tile transposed to [d][v] (pad TV+1 so reads v=tx+32k are conflict-free)
  {
    for (int t = threadIdx.x; t < TV * Dn / 4; t += 256) {
      int e = t * 4;            // element in [v][d] order
      int v = e >> 6;           // / Dn
      int d = e & 63;
      float4 x = *(const float4*)(ebase + (size_t)v * Dn + d);
      semb[(d + 0) * (TV + 1) + v] = x.x;
      semb[(d + 1) * (TV + 1) + v] = x.y;
      semb[(d + 2) * (TV + 1) + v] = x.z;
      semb[(d + 3) * (TV + 1) + v] = x.w;
    }
  }
  __syncthreads();

  int tx = threadIdx.x & 31;
  int ty = threadIdx.x >> 5;    // 0..7
  int mt = ty * THM;

  float acc[THM][THV];
#pragma unroll
  for (int r = 0; r < THM; ++r)
#pragma unroll
    for (int k = 0; k < THV; ++k) acc[r][k] = 0.0f;

#pragma unroll 4
  for (int d = 0; d < Dn; ++d) {
    float ev[THV];
#pragma unroll
    for (int k = 0; k < THV; ++k) ev[k] = semb[d * (TV + 1) + tx + 32 * k];
#pragma unroll
    for (int r = 0; r < THM; ++r) {
      float qv = sq[(mt + r) * Dn + d];   // wave-broadcast (2 distinct addrs/wave)
#pragma unroll
      for (int k = 0; k < THV; ++k) acc[r][k] += qv * ev[k];
    }
  }

  // write coalesced: lanes tx cover 32 consecutive v
  float* obase = scores + ((size_t)bblk * SEQn + m0) * Vn + v0;
#pragma unroll
  for (int r = 0; r < THM; ++r) {
#pragma unroll
    for (int k = 0; k < THV; ++k)
      obase[(size_t)(mt + r) * Vn + tx + 32 * k] = acc[r][k];
  }
}

// ---------------- Phase 2: gather
// out[p,i,j] = scores[b_p, r_p*BS + i, info[p,i,j]]
// one block per p: 1024 elements, 256 threads x (int4 load, 4 gathers, float4 store)
__global__ __launch_bounds__(256) void gather_kernel(
    const float* __restrict__ scores, const int* __restrict__ info,
    const int* __restrict__ idxs_batch, const int* __restrict__ idxs_row,
    float* __restrict__ out)
{
  int p = blockIdx.x;
  int b = idxs_batch[p];          // scalar (uniform per block)
  int r = idxs_row[p];
  const float* srow = scores + ((size_t)b * SEQn + (size_t)r * BSn) * Vn;

  int t = threadIdx.x;
  const int4* in4 = (const int4*)(info + (size_t)p * (BSn * BSn));
  float4*     o4  = (float4*)(out + (size_t)p * (BSn * BSn));

  int4 iv = in4[t];
  const float* row = srow + (size_t)(t >> 3) * Vn;   // i = (t*4)>>5 = t>>3
  float4 o;
  o.x = row[iv.x];
  o.y = row[iv.y];
  o.z = row[iv.z];
  o.w = row[iv.w];
  o4[t] = o;
}

extern "C" void kernel_launch(void* const* d_in, const int* in_sizes, int n_in,
                              void* d_out, int out_size, void* d_ws, size_t ws_size,
                              hipStream_t stream) {
  const float* q          = (const float*)d_in[0];
  const float* emb        = (const float*)d_in[1];
  const int*   info       = (const int*)d_in[2];
  const int*   idxs_batch = (const int*)d_in[3];
  const int*   idxs_row   = (const int*)d_in[4];
  int P = in_sizes[3];            // 33024

  float* scores = (float*)d_ws;   // needs B*SEQ*V*4 = 32 MiB of workspace
  float* out    = (float*)d_out;

  int gemm_blocks = (SEQn / TM) * Bn * (Vn / TV);   // 1024
  scores_kernel<<<gemm_blocks, 256, 0, stream>>>(q, emb, scores);
  gather_kernel<<<P, 256, 0, stream>>>(scores, info, idxs_batch, idxs_row, out);
}

// Round 2
// 272.014 us; speedup vs baseline: 1.1118x; 1.1118x over previous
//
#include <hip/hip_runtime.h>

// Problem constants: B=4, SEQ=4096, D=64, BS=32, V=512, R=128, P=33024
#define Bn   4
#define SEQn 4096
#define Dn   64
#define BSn  32
#define Vn   512
#define Rn   128

// ---------------- Phase 1: scores[b][m][v] = sum_d q[b][m][d] * emb[b][v][d]
// Block tile: 64 m x 128 v, 256 threads, per-thread 8m x 4v register tile.
// LDS is [d]-major so the inner loop is 2x b128 (q, broadcast) + 1x b128 (emb,
// conflict-free: lane tx reads floats 4tx..4tx+3 -> banks 4tx..4tx+3 mod 32).
#define TM   64
#define TVb  128
#define QP   68    // q LDS leading dim  (64+4: keeps b128 16B-aligned)
#define EP   132   // emb LDS leading dim (128+4)

__global__ __launch_bounds__(256) void scores_kernel(
    const float* __restrict__ q, const float* __restrict__ emb,
    float* __restrict__ scores)
{
  __shared__ float sq[Dn * QP];   // [d][m], ~17.4 KB
  __shared__ float se[Dn * EP];   // [d][v], ~33.8 KB   (total ~51 KB -> 3 blk/CU)

  int bx   = blockIdx.x;
  int vblk = bx & 3;            // V/TVb = 4
  int bblk = (bx >> 2) & 3;     // B = 4
  int mblk = bx >> 4;           // SEQ/TM = 64
  int m0 = mblk * TM;
  int v0 = vblk * TVb;

  const float* qbase = q   + ((size_t)bblk * SEQn + m0) * Dn;
  const float* ebase = emb + ((size_t)bblk * Vn   + v0) * Dn;

  int t = threadIdx.x;
  // stage q tile transposed to [d][m]
  for (int idx = t; idx < TM * Dn / 4; idx += 256) {
    int e = idx * 4;
    int m = e >> 6;          // / Dn
    int d = e & 63;
    float4 x = *(const float4*)(qbase + (size_t)m * Dn + d);
    sq[(d + 0) * QP + m] = x.x;
    sq[(d + 1) * QP + m] = x.y;
    sq[(d + 2) * QP + m] = x.z;
    sq[(d + 3) * QP + m] = x.w;
  }
  // stage emb tile transposed to [d][v]
  for (int idx = t; idx < TVb * Dn / 4; idx += 256) {
    int e = idx * 4;
    int v = e >> 6;
    int d = e & 63;
    float4 x = *(const float4*)(ebase + (size_t)v * Dn + d);
    se[(d + 0) * EP + v] = x.x;
    se[(d + 1) * EP + v] = x.y;
    se[(d + 2) * EP + v] = x.z;
    se[(d + 3) * EP + v] = x.w;
  }
  __syncthreads();

  int tx = t & 31;              // v quad: v_local = 4*tx
  int ty = t >> 5;              // m octet: m_local = 8*ty
  int ml = ty * 8;
  int vl = tx * 4;

  float acc[8][4];
#pragma unroll
  for (int r = 0; r < 8; ++r)
#pragma unroll
    for (int k = 0; k < 4; ++k) acc[r][k] = 0.0f;

#pragma unroll 4
  for (int d = 0; d < Dn; ++d) {
    float4 qa = *(const float4*)&sq[d * QP + ml];       // broadcast
    float4 qb = *(const float4*)&sq[d * QP + ml + 4];   // broadcast
    float4 ev = *(const float4*)&se[d * EP + vl];       // conflict-free
    float qr[8] = {qa.x, qa.y, qa.z, qa.w, qb.x, qb.y, qb.z, qb.w};
    float ek[4] = {ev.x, ev.y, ev.z, ev.w};
#pragma unroll
    for (int r = 0; r < 8; ++r)
#pragma unroll
      for (int k = 0; k < 4; ++k) acc[r][k] += qr[r] * ek[k];
  }

  float* obase = scores + ((size_t)bblk * SEQn + m0) * Vn + v0;
#pragma unroll
  for (int r = 0; r < 8; ++r) {
    float4 st = {acc[r][0], acc[r][1], acc[r][2], acc[r][3]};
    *(float4*)(obase + (size_t)(ml + r) * Vn + vl) = st;   // 16B/lane coalesced
  }
}

// ---------------- Phase 2: gather via LDS slab
// tril structure: for batch b, row r, the p's are contiguous:
//   p = b*8256 + r*(r+1)/2 + c,  c in [0, r]
// One block per (b, r, chunk of up to 16 p's). Stage the 32x512 score slab
// (64 KB) into LDS once, then each p: coalesced int4 info load, 4 LDS
// gathers, coalesced float4 store.
#define CHUNK 16
#define PPB   8256   // p's per batch = R*(R+1)/2

__global__ __launch_bounds__(256) void gather_kernel(
    const float* __restrict__ scores, const int* __restrict__ info,
    float* __restrict__ out)
{
  __shared__ float slab[BSn * Vn];   // 64 KB -> 2 blocks/CU

  int cid = blockIdx.x;   // [0, 576)
  int b   = blockIdx.y;

  // group g covers rows 16g..16g+15, each with (g+1) chunks;
  // group start cid = 8*g*(g+1)
  int g = 0;
  while (8 * (g + 1) * (g + 2) <= cid) ++g;
  int local = cid - 8 * g * (g + 1);
  int rq    = local / (g + 1);
  int chunk = local - rq * (g + 1);
  int r     = 16 * g + rq;
  int np    = min(CHUNK, (r + 1) - chunk * CHUNK);
  size_t p0 = (size_t)b * PPB + ((size_t)r * (r + 1)) / 2 + (size_t)chunk * CHUNK;

  // stage slab: rows r*32 .. r*32+31, all 512 v
  {
    const float4* src = (const float4*)(scores + ((size_t)b * SEQn + (size_t)r * BSn) * Vn);
    float4* dst = (float4*)slab;
    for (int idx = threadIdx.x; idx < BSn * Vn / 4; idx += 256) dst[idx] = src[idx];
  }
  __syncthreads();

  int t = threadIdx.x;
  int rowoff = (t >> 3) << 9;       // i = (4t)>>5 = t>>3 ; i*512
  const int4* info4 = (const int4*)info;
  float4*     out4  = (float4*)out;

  if (np == CHUNK) {
    int4 iv[CHUNK];
#pragma unroll
    for (int k = 0; k < CHUNK; ++k)
      iv[k] = info4[(p0 + k) * 256 + t];
#pragma unroll
    for (int k = 0; k < CHUNK; ++k) {
      float4 o;
      o.x = slab[rowoff + iv[k].x];
      o.y = slab[rowoff + iv[k].y];
      o.z = slab[rowoff + iv[k].z];
      o.w = slab[rowoff + iv[k].w];
      out4[(p0 + k) * 256 + t] = o;
    }
  } else {
    for (int k = 0; k < np; ++k) {
      int4 v = info4[(p0 + k) * 256 + t];
      float4 o;
      o.x = slab[rowoff + v.x];
      o.y = slab[rowoff + v.y];
      o.z = slab[rowoff + v.z];
      o.w = slab[rowoff + v.w];
      out4[(p0 + k) * 256 + t] = o;
    }
  }
}

extern "C" void kernel_launch(void* const* d_in, const int* in_sizes, int n_in,
                              void* d_out, int out_size, void* d_ws, size_t ws_size,
                              hipStream_t stream) {
  const float* q    = (const float*)d_in[0];
  const float* emb  = (const float*)d_in[1];
  const int*   info = (const int*)d_in[2];
  // d_in[3] = idxs_batch, d_in[4] = idxs_row — derivable from tril structure.

  float* scores = (float*)d_ws;   // B*SEQ*V*4 = 32 MiB
  float* out    = (float*)d_out;

  int gemm_blocks = (SEQn / TM) * Bn * (Vn / TVb);   // 1024
  scores_kernel<<<gemm_blocks, 256, 0, stream>>>(q, emb, scores);

  // chunks per batch: sum over r of ceil((r+1)/16) = 576
  dim3 ggrid(576, Bn);
  gather_kernel<<<ggrid, 256, 0, stream>>>(scores, info, out);
}

// Round 3
// 268.097 us; speedup vs baseline: 1.1280x; 1.0146x over previous
//
#include <hip/hip_runtime.h>

// Problem constants: B=4, SEQ=4096, D=64, BS=32, V=512, R=128, P=33024
#define Bn   4
#define SEQn 4096
#define Dn   64
#define BSn  32
#define Vn   512
#define Rn   128
#define PPB  8256   // p's per batch = R*(R+1)/2

// ---------------- Phase 1: scores[b][m][v] = sum_d q[b][m][d] * emb[b][v][d]
// Block tile: 64 m x 128 v, 256 threads, per-thread 8m x 4v register tile.
#define TM   64
#define TVb  128
#define QP   68    // q LDS leading dim  (64+4: keeps b128 16B-aligned)
#define EP   132   // emb LDS leading dim (128+4)

__global__ __launch_bounds__(256) void scores_kernel(
    const float* __restrict__ q, const float* __restrict__ emb,
    float* __restrict__ scores)
{
  __shared__ float sq[Dn * QP];   // [d][m]
  __shared__ float se[Dn * EP];   // [d][v]

  int bx   = blockIdx.x;
  int vblk = bx & 3;            // V/TVb = 4
  int bblk = (bx >> 2) & 3;     // B = 4
  int mblk = bx >> 4;           // SEQ/TM = 64
  int m0 = mblk * TM;
  int v0 = vblk * TVb;

  const float* qbase = q   + ((size_t)bblk * SEQn + m0) * Dn;
  const float* ebase = emb + ((size_t)bblk * Vn   + v0) * Dn;

  int t = threadIdx.x;
  for (int idx = t; idx < TM * Dn / 4; idx += 256) {
    int e = idx * 4;
    int m = e >> 6;
    int d = e & 63;
    float4 x = *(const float4*)(qbase + (size_t)m * Dn + d);
    sq[(d + 0) * QP + m] = x.x;
    sq[(d + 1) * QP + m] = x.y;
    sq[(d + 2) * QP + m] = x.z;
    sq[(d + 3) * QP + m] = x.w;
  }
  for (int idx = t; idx < TVb * Dn / 4; idx += 256) {
    int e = idx * 4;
    int v = e >> 6;
    int d = e & 63;
    float4 x = *(const float4*)(ebase + (size_t)v * Dn + d);
    se[(d + 0) * EP + v] = x.x;
    se[(d + 1) * EP + v] = x.y;
    se[(d + 2) * EP + v] = x.z;
    se[(d + 3) * EP + v] = x.w;
  }
  __syncthreads();

  int tx = t & 31;
  int ty = t >> 5;
  int ml = ty * 8;
  int vl = tx * 4;

  float acc[8][4];
#pragma unroll
  for (int r = 0; r < 8; ++r)
#pragma unroll
    for (int k = 0; k < 4; ++k) acc[r][k] = 0.0f;

#pragma unroll 4
  for (int d = 0; d < Dn; ++d) {
    float4 qa = *(const float4*)&sq[d * QP + ml];
    float4 qb = *(const float4*)&sq[d * QP + ml + 4];
    float4 ev = *(const float4*)&se[d * EP + vl];
    float qr[8] = {qa.x, qa.y, qa.z, qa.w, qb.x, qb.y, qb.z, qb.w};
    float ek[4] = {ev.x, ev.y, ev.z, ev.w};
#pragma unroll
    for (int r = 0; r < 8; ++r)
#pragma unroll
      for (int k = 0; k < 4; ++k) acc[r][k] += qr[r] * ek[k];
  }

  float* obase = scores + ((size_t)bblk * SEQn + m0) * Vn + v0;
#pragma unroll
  for (int r = 0; r < 8; ++r) {
    float4 st = {acc[r][0], acc[r][1], acc[r][2], acc[r][3]};
    *(float4*)(obase + (size_t)(ml + r) * Vn + vl) = st;
  }
}

// ---------------- Phase 2: gather via LDS slab, 512-thread blocks
// p = b*8256 + r*(r+1)/2 + c,  c in [0, r]
// Block = (b, r, chunk of up to 16 p's). 512 threads: sub = tid>>8 picks which
// p of a pair, so 2 p's per iteration, 8 iterations. Info int4s preloaded to
// registers BEFORE the barrier so they overlap slab staging.
// LDS 64 KB -> 2 blocks/CU -> 16 waves/CU (50% occupancy vs 18% at 256 thr).
#define GCHUNK 16

__global__ __launch_bounds__(512) void gather_kernel(
    const float* __restrict__ scores, const int* __restrict__ info,
    float* __restrict__ out)
{
  __shared__ float slab[BSn * Vn];   // 64 KB

  int cid = blockIdx.x;   // [0, 576)
  int b   = blockIdx.y;

  // group g covers rows 16g..16g+15, each with (g+1) chunks; start = 8g(g+1)
  int g = 0;
  while (8 * (g + 1) * (g + 2) <= cid) ++g;
  int local = cid - 8 * g * (g + 1);
  int rq    = local / (g + 1);
  int chunk = local - rq * (g + 1);
  int r     = 16 * g + rq;
  int np    = min(GCHUNK, (r + 1) - chunk * GCHUNK);
  size_t p0 = (size_t)b * PPB + ((size_t)r * (r + 1)) / 2 + (size_t)chunk * GCHUNK;

  int tid = threadIdx.x;
  int sub = tid >> 8;          // which p of the pair
  int t   = tid & 255;
  int rowoff = (t >> 3) << 9;  // i = t>>3 ; i*512

  const int4* info4 = (const int4*)info;
  float4*     out4  = (float4*)out;

  // preload info — independent of slab, overlaps staging
  int4 iv[8];
#pragma unroll
  for (int k = 0; k < 8; ++k) {
    int pp = 2 * k + sub;
    size_t p = p0 + (pp < np ? pp : 0);   // clamp keeps loads in-bounds
    iv[k] = info4[p * 256 + t];
  }

  // stage slab: rows r*32 .. r*32+31, all 512 v
  {
    const float4* src = (const float4*)(scores + ((size_t)b * SEQn + (size_t)r * BSn) * Vn);
    float4* dst = (float4*)slab;
    for (int idx = tid; idx < BSn * Vn / 4; idx += 512) dst[idx] = src[idx];
  }
  __syncthreads();

#pragma unroll
  for (int k = 0; k < 8; ++k) {
    int pp = 2 * k + sub;
    if (pp < np) {
      float4 o;
      o.x = slab[rowoff + iv[k].x];
      o.y = slab[rowoff + iv[k].y];
      o.z = slab[rowoff + iv[k].z];
      o.w = slab[rowoff + iv[k].w];
      out4[(p0 + pp) * 256 + t] = o;
    }
  }
}

extern "C" void kernel_launch(void* const* d_in, const int* in_sizes, int n_in,
                              void* d_out, int out_size, void* d_ws, size_t ws_size,
                              hipStream_t stream) {
  const float* q    = (const float*)d_in[0];
  const float* emb  = (const float*)d_in[1];
  const int*   info = (const int*)d_in[2];
  // d_in[3]/d_in[4] (idxs_batch/idxs_row) derivable from tril structure.

  float* scores = (float*)d_ws;   // B*SEQ*V*4 = 32 MiB
  float* out    = (float*)d_out;

  int gemm_blocks = (SEQn / TM) * Bn * (Vn / TVb);   // 1024
  scores_kernel<<<gemm_blocks, 256, 0, stream>>>(q, emb, scores);

  dim3 ggrid(576, Bn);   // sum_r ceil((r+1)/16) = 576 chunks per batch
  gather_kernel<<<ggrid, 512, 0, stream>>>(scores, info, out);
}